// Round 4
// baseline (3791.152 us; speedup 1.0000x reference)
//
#include <hip/hip_runtime.h>
#include <hip/hip_bf16.h>
#include <math.h>

// Problem constants (fixed by setup_inputs)
#define BB 128
#define DD 512
#define HH 1024
#define NB 32     // num_coeff_per_dim
#define MM 63     // 2N-1 simpson points
#define TT 16
#define ITERS 10
#define NBLOCKS 1024

// ws layout (float units)
#define OFF_U       0        // 32 fp32
#define OFF_TTRUE   64       // 64 fp32 (tt[63]=0)
#define OFF_PHIOUT  128      // 512 fp32
#define OFF_PHIF_BF 1024     // bf16 [64 m][32 n]  (row 63 = 0)   = 1024 floats
#define OFF_QT_BF   2048     // bf16 [32 j][64 m]  (col 63 = 0)   = 1024 floats
#define OFF_BAR     3584     // grid-barrier counter (1 u32)
#define HDRF        4096
#define OFF_BN      HDRF                     // fp32 [B][512][32]  = 2097152
#define OFF_BCT     (OFF_BN + 2097152)       // bf16 [B][32][512]  = 1048576 f
#define OFF_PT      (OFF_BCT + 1048576)      // bf16 [B][32][1024] = 2097152 f
#define OFF_W1T     (OFF_PT + 2097152)       // bf16 [1024][512]   = 262144 f
#define OFF_W2T     (OFF_W1T + 262144)       // bf16 [512][1024]   = 262144 f
// end = 5771264 floats = 23.1 MB

typedef __attribute__((ext_vector_type(8))) short bf16x8;
typedef __attribute__((ext_vector_type(4))) float f32x4;

static __device__ __forceinline__ unsigned short f2bf(float f) {
    unsigned int x = __builtin_bit_cast(unsigned int, f);
    unsigned int r = x + 0x7FFFu + ((x >> 16) & 1u);   // RNE
    return (unsigned short)(r >> 16);
}

static __device__ __forceinline__ void store4bf(unsigned short* p,
                                                float v0, float v1, float v2, float v3) {
    unsigned int lo = (unsigned int)f2bf(v0) | ((unsigned int)f2bf(v1) << 16);
    unsigned int hi = (unsigned int)f2bf(v2) | ((unsigned int)f2bf(v3) << 16);
    uint2 u; u.x = lo; u.y = hi;
    *(uint2*)p = u;   // 8B-aligned by construction
}

static __device__ __forceinline__ float tanh_fast(float x) {
    float e = exp2f(x * 2.88539008177793f);   // 2*log2(e)
    return 1.0f - 2.0f / (e + 1.0f);
}

// Hand-rolled grid barrier (graph-capture-safe; no cooperative launch).
// Monotone counter in ws: leader release-adds 1, acquire-spins to k*NBLOCKS.
// Safe because all 1024 blocks are co-resident by construction:
// VGPR<=128 (launch_bounds), LDS 26.6KB (<160/4), 256 thr -> >=4 blocks/CU.
static __device__ __forceinline__ void grid_barrier(unsigned* cnt, unsigned target) {
    __syncthreads();
    if (threadIdx.x == 0) {
        __threadfence();   // agent-scope release of this block's prior writes
        __hip_atomic_fetch_add(cnt, 1u, __ATOMIC_RELEASE, __HIP_MEMORY_SCOPE_AGENT);
        while (__hip_atomic_load(cnt, __ATOMIC_ACQUIRE, __HIP_MEMORY_SCOPE_AGENT) < target) {
            __builtin_amdgcn_s_sleep(2);
        }
    }
    __syncthreads();
}

// ---------------------------------------------------------------------------
// Setup (separate 1-block launch: 66 KB LDS would break mega co-residency).
// Also zeroes the grid-barrier counter each replay (ws is re-poisoned).
// ---------------------------------------------------------------------------
__global__ __launch_bounds__(256) void setup_kernel(const float* __restrict__ t_span,
                                                    float* __restrict__ ws) {
    __shared__ double tsim[MM];
    __shared__ double ttrue_d[MM];
    __shared__ double wid[31];
    __shared__ double phid[NB * MM];   // [n][m]
    __shared__ double aug[NB * 64];    // [Phi | I]
    __shared__ double mlt[NB];
    __shared__ double Rl[MM * NB];
    __shared__ double Qd[MM * NB];     // [m][j]
    __shared__ int    piv_s;

    const int t    = threadIdx.x;  // 256 threads
    const int lane = t & 63;
    const int rgrp = t >> 6;
    const double PI = 3.14159265358979323846;
    const double t0 = (double)t_span[0];
    const double t1 = (double)t_span[TT - 1];

    if (t == 0)
        __hip_atomic_store((unsigned*)(ws + OFF_BAR), 0u,
                           __ATOMIC_RELAXED, __HIP_MEMORY_SCOPE_AGENT);

    if (t < MM) {
        double v;
        if ((t & 1) == 0) {
            int j = t >> 1;
            v = -cos(PI * (double)j / (double)(NB - 1));
        } else {
            int i = t >> 1;
            double a = -cos(PI * (double)i / (double)(NB - 1));
            double b = -cos(PI * (double)(i + 1) / (double)(NB - 1));
            v = 0.5 * (a + b);
        }
        tsim[t] = v;
        ttrue_d[t] = t0 + 0.5 * (t1 - t0) * (v + 1.0);
    }
    __syncthreads();
    if (t < 31) wid[t] = (ttrue_d[2 * t + 2] - ttrue_d[2 * t]) / 6.0;
    if (t < MM) ws[OFF_TTRUE + t] = (float)ttrue_d[t];
    if (t == 63) ws[OFF_TTRUE + 63] = 0.0f;

    if (t < MM) {
        double x = tsim[t];
        double r0 = 1.0, r1 = x;
        phid[0 * MM + t] = r0;
        phid[1 * MM + t] = r1;
        for (int n = 2; n < NB; n++) {
            double r2 = 2.0 * x * r1 - r0;
            phid[n * MM + t] = r2;
            r0 = r1; r1 = r2;
        }
    }
    __syncthreads();

    {   // phif_bf [m 64][n 32], row 63 = 0
        unsigned short* pf = (unsigned short*)(ws + OFF_PHIF_BF);
        for (int f = t; f < 64 * 32; f += 256) {
            int m = f >> 5, n = f & 31;
            pf[f] = f2bf(m < MM ? (float)phid[n * MM + m] : 0.0f);
        }
    }

    for (int f = t; f < NB * 64; f += 256) {
        int r = f >> 6, c = f & 63;
        double v;
        if (c < NB) v = phid[r * MM + 2 * c];
        else        v = ((c - NB) == r) ? 1.0 : 0.0;
        aug[f] = v;
    }
    __syncthreads();

    for (int k = 0; k < NB; k++) {
        if (t < 32) {
            double v = (t >= k) ? fabs(aug[t * 64 + k]) : -1.0;
            int idx = t;
            #pragma unroll
            for (int off = 16; off >= 1; off >>= 1) {
                double ov = __shfl_xor(v, off);
                int    oi = __shfl_xor(idx, off);
                if (ov > v) { v = ov; idx = oi; }
            }
            if (t == 0) piv_s = idx;
        }
        __syncthreads();
        const int p = piv_s;
        if (t < 64) {
            double pv   = aug[p * 64 + k];
            double rowp = aug[p * 64 + t];
            double rowk = aug[k * 64 + t];
            aug[k * 64 + t] = rowp / pv;
            if (p != k) aug[p * 64 + t] = rowk;
        }
        __syncthreads();
        if (t < 32) mlt[t] = (t == k) ? 0.0 : aug[t * 64 + k];
        __syncthreads();
        {
            double pk = aug[k * 64 + lane];
            #pragma unroll
            for (int i = 0; i < 8; i++) {
                int r = rgrp * 8 + i;
                aug[r * 64 + lane] -= mlt[r] * pk;
            }
        }
        __syncthreads();
    }

    if (t < MM) {
        double acc = 0.0;
        Rl[t * NB + 0] = 0.0;
        for (int i = 1; i < NB; i++) {
            int ip = i - 1;
            double w = 0.0;
            if (t == 2 * ip)     w += wid[ip];
            if (t == 2 * ip + 1) w += 4.0 * wid[ip];
            if (t == 2 * ip + 2) w += wid[ip];
            acc += w;
            Rl[t * NB + i] = acc;
        }
    }
    __syncthreads();

    for (int f = t; f < MM * NB; f += 256) {
        int m = f >> 5, j = f & 31;
        double s = 0.0;
        for (int i = 0; i < NB; i++) s += Rl[m * NB + i] * aug[i * 64 + 32 + j];
        Qd[f] = s;
    }
    __syncthreads();

    {   // qt_bf [j 32][m 64], col 63 = 0
        unsigned short* qt = (unsigned short*)(ws + OFF_QT_BF);
        for (int f = t; f < 32 * 64; f += 256) {
            int j = f >> 6, m = f & 63;
            qt[f] = f2bf(m < MM ? (float)Qd[m * NB + j] : 0.0f);
        }
    }
    if (t < NB) {
        double s = 0.0;
        for (int i = 0; i < NB; i++) s += aug[i * 64 + 32 + t];
        ws[OFF_U + t] = (float)s;
    }
    if (t < TT) {
        double x = -1.0 + 2.0 * ((double)t_span[t] - t0) / (t1 - t0);
        double r0 = 1.0, r1 = x;
        ws[OFF_PHIOUT + 0 * TT + t] = 1.0f;
        ws[OFF_PHIOUT + 1 * TT + t] = (float)x;
        for (int n = 2; n < NB; n++) {
            double r2 = 2.0 * x * r1 - r0;
            ws[OFF_PHIOUT + n * TT + t] = (float)r2;
            r0 = r1; r1 = r2;
        }
    }
}

// ---------------------------------------------------------------------------
// Mega-kernel device pieces. LDS overlay 26624 B; 4 blocks/CU x 26.6KB
// = 106 KB <= 160 KB; VGPR capped 128 by __launch_bounds__(256,4).
// ---------------------------------------------------------------------------
#define SMEM_BYTES 26624

static __device__ __forceinline__ void transpose_tile(
        const float* __restrict__ in, unsigned short* __restrict__ out,
        int R, int C, int tc, int tr, int t, float* tile /*32x33 f32*/) {
    const int c = tc * 32 + (t & 31);
    #pragma unroll
    for (int i = 0; i < 4; i++) {
        int rl = (t >> 5) + i * 8;
        tile[rl * 33 + (t & 31)] = in[(size_t)(tr * 32 + rl) * C + c];
    }
    __syncthreads();
    #pragma unroll
    for (int i = 0; i < 4; i++) {
        int orl = (t >> 5) + i * 8;
        int orow = tc * 32 + orl;
        int ocol = tr * 32 + (t & 31);
        out[(size_t)orow * R + ocol] = f2bf(tile[(t & 31) * 33 + orl]);
    }
}

static __device__ __forceinline__ void binit_tile(
        const float* __restrict__ Bi, unsigned short* __restrict__ Bct,
        int d0blk, int b, int t, float* tile) {
    const int d0 = d0blk * 32;
    #pragma unroll
    for (int i = 0; i < 4; i++) {
        int f = i * 256 + t;
        int dd = f >> 5, n = f & 31;
        tile[dd * 33 + n] = Bi[((size_t)b * DD + d0 + dd) * NB + n];
    }
    __syncthreads();
    #pragma unroll
    for (int i = 0; i < 4; i++) {
        int f = i * 256 + t;
        int n = f >> 5, dd = f & 31;
        Bct[((size_t)b * NB + n) * DD + d0 + dd] = f2bf(tile[dd * 33 + n]);
    }
}

static __device__ __forceinline__ void k1_part(
        int b, int hblk, int t,
        const unsigned short* __restrict__ Bct,
        const unsigned short* __restrict__ W1t,
        const float* __restrict__ b1,
        const float* __restrict__ ws,
        unsigned short* __restrict__ Pt,
        char* smem_raw) {
    unsigned short* g_sb = (unsigned short*)smem_raw;            // [128][32]  8192 B
    unsigned short* t_sb = (unsigned short*)(smem_raw + 8192);   // [128][72] 18432 B

    const int lane = t & 63;
    const int w    = t >> 6;
    const int q    = lane >> 4;
    const int l15  = lane & 15;
    const int h0   = hblk * 128;
    const int hw   = h0 + w * 32;

    // Phase A: G = Bc^T W1, M=32(n) x N=32(h/wave) x K=512
    f32x4 acc[2][2] = {};
    const unsigned short* A0 = Bct + (size_t)b * NB * DD;
    #pragma unroll 4
    for (int d0 = 0; d0 < DD; d0 += 32) {
        bf16x8 a0 = *(const bf16x8*)(A0 + (size_t)(l15) * DD + d0 + q * 8);
        bf16x8 a1 = *(const bf16x8*)(A0 + (size_t)(16 + l15) * DD + d0 + q * 8);
        bf16x8 bb0 = *(const bf16x8*)(W1t + (size_t)(hw + l15) * DD + d0 + q * 8);
        bf16x8 bb1 = *(const bf16x8*)(W1t + (size_t)(hw + 16 + l15) * DD + d0 + q * 8);
        acc[0][0] = __builtin_amdgcn_mfma_f32_16x16x32_bf16(a0, bb0, acc[0][0], 0, 0, 0);
        acc[0][1] = __builtin_amdgcn_mfma_f32_16x16x32_bf16(a0, bb1, acc[0][1], 0, 0, 0);
        acc[1][0] = __builtin_amdgcn_mfma_f32_16x16x32_bf16(a1, bb0, acc[1][0], 0, 0, 0);
        acc[1][1] = __builtin_amdgcn_mfma_f32_16x16x32_bf16(a1, bb1, acc[1][1], 0, 0, 0);
    }
    #pragma unroll
    for (int mt = 0; mt < 2; mt++)
        #pragma unroll
        for (int nt = 0; nt < 2; nt++) {
            int hl = w * 32 + nt * 16 + l15;
            store4bf(&g_sb[hl * 32 + mt * 16 + q * 4],
                     acc[mt][nt][0], acc[mt][nt][1], acc[mt][nt][2], acc[mt][nt][3]);
        }
    __syncthreads();

    // Z = Phi_f^T G : M=64(m) x N=32(h/wave) x K=32(n)
    f32x4 zacc[4][2] = {};
    const unsigned short* PF = (const unsigned short*)(ws + OFF_PHIF_BF);
    bf16x8 gb[2];
    #pragma unroll
    for (int nt = 0; nt < 2; nt++)
        gb[nt] = *(const bf16x8*)(&g_sb[(w * 32 + nt * 16 + l15) * 32 + q * 8]);
    #pragma unroll
    for (int mt = 0; mt < 4; mt++) {
        bf16x8 af = *(const bf16x8*)(PF + (mt * 16 + l15) * 32 + q * 8);
        zacc[mt][0] = __builtin_amdgcn_mfma_f32_16x16x32_bf16(af, gb[0], zacc[mt][0], 0, 0, 0);
        zacc[mt][1] = __builtin_amdgcn_mfma_f32_16x16x32_bf16(af, gb[1], zacc[mt][1], 0, 0, 0);
    }

    const float* TTp = ws + OFF_TTRUE;
    float b1v[2] = { b1[hw + l15], b1[hw + 16 + l15] };
    #pragma unroll
    for (int mt = 0; mt < 4; mt++) {
        float4 ttv = *(const float4*)(TTp + mt * 16 + q * 4);
        #pragma unroll
        for (int nt = 0; nt < 2; nt++) {
            int hl = w * 32 + nt * 16 + l15;
            float v0 = tanh_fast(zacc[mt][nt][0] + ttv.x * b1v[nt]);
            float v1 = tanh_fast(zacc[mt][nt][1] + ttv.y * b1v[nt]);
            float v2 = tanh_fast(zacc[mt][nt][2] + ttv.z * b1v[nt]);
            float v3 = tanh_fast(zacc[mt][nt][3] + ttv.w * b1v[nt]);
            store4bf(&t_sb[hl * 72 + mt * 16 + q * 4], v0, v1, v2, v3);
        }
    }
    __syncthreads();

    // P = Q^T T : M=32(j) x N=32(h/wave) x K=64(m)
    f32x4 pacc[2][2] = {};
    const unsigned short* QT = (const unsigned short*)(ws + OFF_QT_BF);
    #pragma unroll
    for (int ks = 0; ks < 2; ks++) {
        bf16x8 bt[2];
        #pragma unroll
        for (int nt = 0; nt < 2; nt++)
            bt[nt] = *(const bf16x8*)(&t_sb[(w * 32 + nt * 16 + l15) * 72 + ks * 32 + q * 8]);
        #pragma unroll
        for (int jt = 0; jt < 2; jt++) {
            bf16x8 aq = *(const bf16x8*)(QT + (jt * 16 + l15) * 64 + ks * 32 + q * 8);
            pacc[jt][0] = __builtin_amdgcn_mfma_f32_16x16x32_bf16(aq, bt[0], pacc[jt][0], 0, 0, 0);
            pacc[jt][1] = __builtin_amdgcn_mfma_f32_16x16x32_bf16(aq, bt[1], pacc[jt][1], 0, 0, 0);
        }
    }

    #pragma unroll
    for (int jt = 0; jt < 2; jt++)
        #pragma unroll
        for (int nt = 0; nt < 2; nt++) {
            int hg = hw + nt * 16 + l15;
            #pragma unroll
            for (int r = 0; r < 4; r++) {
                int j = jt * 16 + q * 4 + r;
                Pt[((size_t)b * NB + j) * HH + hg] = f2bf(pacc[jt][nt][r]);
            }
        }
}

// k2: Bn[b,d,j] = sum_h P[b,j,h] W2t[d,h] + y u[j].
// 1024 blocks: N=64 d per block, K=1024 split over wave pairs (h halves),
// LDS partial reduce; waves stay fully busy (was: 512-block half-idle grid).
static __device__ __forceinline__ void k2_part(
        int b, int dblk, int t, bool last,
        const unsigned short* __restrict__ Pt,
        const unsigned short* __restrict__ W2t,
        const float* __restrict__ y_init,
        const float* __restrict__ ws,
        float* __restrict__ Bn,
        unsigned short* __restrict__ Bct,
        char* smem_raw) {
    float* red = (float*)smem_raw;             // 2 x 1024 f32 = 8192 B
    float* ls  = (float*)(smem_raw + 8192);    // 2 x 32*33 f32 = 8448 B

    const int lane = t & 63;
    const int w    = t >> 6;
    const int q    = lane >> 4;
    const int l15  = lane & 15;
    const int d0   = dblk * 64;
    const int dw   = d0 + (w & 1) * 32;
    const int hh0  = (w >> 1) * 512;

    f32x4 acc[2][2] = {};
    const unsigned short* A0 = Pt + (size_t)b * NB * HH + hh0;
    #pragma unroll 4
    for (int hc = 0; hc < 512; hc += 32) {
        bf16x8 a0 = *(const bf16x8*)(A0 + (size_t)(l15) * HH + hc + q * 8);
        bf16x8 a1 = *(const bf16x8*)(A0 + (size_t)(16 + l15) * HH + hc + q * 8);
        bf16x8 bb0 = *(const bf16x8*)(W2t + (size_t)(dw + l15) * HH + hh0 + hc + q * 8);
        bf16x8 bb1 = *(const bf16x8*)(W2t + (size_t)(dw + 16 + l15) * HH + hh0 + hc + q * 8);
        acc[0][0] = __builtin_amdgcn_mfma_f32_16x16x32_bf16(a0, bb0, acc[0][0], 0, 0, 0);
        acc[0][1] = __builtin_amdgcn_mfma_f32_16x16x32_bf16(a0, bb1, acc[0][1], 0, 0, 0);
        acc[1][0] = __builtin_amdgcn_mfma_f32_16x16x32_bf16(a1, bb0, acc[1][0], 0, 0, 0);
        acc[1][1] = __builtin_amdgcn_mfma_f32_16x16x32_bf16(a1, bb1, acc[1][1], 0, 0, 0);
    }

    if (w >= 2) {   // dump partials (h-half 512..1023)
        float* rp = red + (w & 1) * 1024;
        #pragma unroll
        for (int mt = 0; mt < 2; mt++)
            #pragma unroll
            for (int nt = 0; nt < 2; nt++)
                *(f32x4*)(rp + (mt * 2 + nt) * 256 + lane * 4) = acc[mt][nt];
    }
    __syncthreads();

    if (w < 2) {
        float* rp = red + w * 1024;
        #pragma unroll
        for (int mt = 0; mt < 2; mt++)
            #pragma unroll
            for (int nt = 0; nt < 2; nt++)
                acc[mt][nt] += *(const f32x4*)(rp + (mt * 2 + nt) * 256 + lane * 4);

        const float* U = ws + OFF_U;
        float yv[2] = { y_init[(size_t)b * DD + dw + l15],
                        y_init[(size_t)b * DD + dw + 16 + l15] };
        #pragma unroll
        for (int mt = 0; mt < 2; mt++) {
            float4 uv = *(const float4*)(U + mt * 16 + q * 4);
            #pragma unroll
            for (int nt = 0; nt < 2; nt++) {
                int dl = nt * 16 + l15;
                #pragma unroll
                for (int r = 0; r < 4; r++) {
                    int j = mt * 16 + q * 4 + r;
                    float uvr = (r == 0) ? uv.x : (r == 1) ? uv.y : (r == 2) ? uv.z : uv.w;
                    float val = acc[mt][nt][r] + yv[nt] * uvr;
                    if (!last) Bct[((size_t)b * NB + j) * DD + dw + dl] = f2bf(val);
                    else       ls[w * 1056 + j * 33 + dl] = val;
                }
            }
        }
    }
    __syncthreads();

    if (last) {   // coalesced fp32 Bn write, all 4 waves (tile = w&1, rows split)
        const int tile = w & 1;
        #pragma unroll
        for (int itr = 0; itr < 8; itr++) {
            int f = ((w >> 1) * 8 + itr) * 64 + lane;
            int d_l = f >> 5, j2 = f & 31;
            Bn[((size_t)b * DD + d0 + tile * 32 + d_l) * NB + j2] = ls[tile * 1056 + j2 * 33 + d_l];
        }
    }
}

static __device__ __forceinline__ void k3_part(
        int bid, int t, const float* __restrict__ ws_c, float* __restrict__ out,
        char* smem_raw) {
    float* rows_s   = (float*)smem_raw;            // 64*33 f32 = 8448 B
    float* phiout_s = (float*)(smem_raw + 8448);   // 512 f32  = 2048 B

    const int r0 = bid * 64;
    const float* Bf = ws_c + OFF_BN;

    for (int f = t; f < NB * TT; f += 256) phiout_s[f] = ws_c[OFF_PHIOUT + f];

    float vals[8];
    {
        int f = t;
        #pragma unroll
        for (int i = 0; i < 8; i++, f += 256) {
            float v = Bf[(size_t)r0 * NB + f];
            rows_s[(f >> 5) * 33 + (f & 31)] = v;
            vals[i] = v;
        }
    }
    float* out1 = out + (size_t)TT * BB * DD;
    {
        int f = t;
        #pragma unroll
        for (int i = 0; i < 8; i++, f += 256) out1[(size_t)r0 * NB + f] = vals[i];
    }
    __syncthreads();

    #pragma unroll
    for (int i = 0; i < 4; i++) {
        int idx = i * 256 + t;
        int tt = idx >> 6, rl = idx & 63;
        float s = 0.f;
        #pragma unroll
        for (int n = 0; n < NB; n++)
            s += rows_s[rl * 33 + n] * phiout_s[n * TT + tt];
        out[(size_t)tt * (BB * DD) + r0 + rl] = s;
    }
}

// ---------------------------------------------------------------------------
// Mega-kernel: prologue (transposes + binit) + 10x(k1,k2) + k3; hand-rolled
// grid barriers replace 23 kernel boundaries. Grid 1024x256 = 4 blocks/CU.
// ---------------------------------------------------------------------------
__global__ __launch_bounds__(256, 4) void mega_kernel(
        const float* W1, const float* W2, const float* B_init,
        const float* b1, const float* y_init, float* ws, float* out) {
    __shared__ __align__(16) char smem_raw[SMEM_BYTES];

    const int bid = blockIdx.x;          // 0..1023
    const int t   = threadIdx.x;         // 0..255
    const int b   = bid & 127;           // low bits: per-b XCD affinity
    const int sub = bid >> 7;            // 0..7 (hblk for k1, dblk for k2)

    unsigned short* __restrict__ W1t = (unsigned short*)(ws + OFF_W1T);
    unsigned short* __restrict__ W2t = (unsigned short*)(ws + OFF_W2T);
    unsigned short* __restrict__ Bct = (unsigned short*)(ws + OFF_BCT);
    unsigned short* __restrict__ Pt  = (unsigned short*)(ws + OFF_PT);
    float*          __restrict__ Bn  = ws + OFF_BN;
    unsigned*       bar              = (unsigned*)(ws + OFF_BAR);
    unsigned        target           = 0;

    // ---- prologue: 3072 tile jobs over 1024 blocks (3 each) ----
    #pragma unroll 1
    for (int g = bid; g < 3072; g += 1024) {
        float* tile = (float*)smem_raw;
        if (g < 512)        transpose_tile(W1, W1t, DD, HH, g & 31, g >> 5, t, tile);
        else if (g < 1024)  { int gg = g - 512;  transpose_tile(W2, W2t, HH, DD, gg & 15, gg >> 4, t, tile); }
        else                { int gg = g - 1024; binit_tile(B_init, Bct, gg & 15, gg >> 4, t, tile); }
        __syncthreads();
    }
    target += NBLOCKS; grid_barrier(bar, target);

    // ---- iterations ----
    #pragma unroll 1
    for (int it = 0; it < ITERS; ++it) {
        k1_part(b, sub, t, Bct, W1t, b1, ws, Pt, smem_raw);
        target += NBLOCKS; grid_barrier(bar, target);
        k2_part(b, sub, t, it == ITERS - 1, Pt, W2t, y_init, ws, Bn, Bct, smem_raw);
        target += NBLOCKS; grid_barrier(bar, target);
    }

    // ---- epilogue ----
    k3_part(bid, t, ws, out, smem_raw);
}

// ---------------------------------------------------------------------------
extern "C" void kernel_launch(void* const* d_in, const int* in_sizes, int n_in,
                              void* d_out, int out_size, void* d_ws, size_t ws_size,
                              hipStream_t stream) {
    const float* t_span = (const float*)d_in[0];
    const float* y_init = (const float*)d_in[1];
    const float* B_init = (const float*)d_in[2];
    const float* W1     = (const float*)d_in[3];
    const float* b1     = (const float*)d_in[4];
    const float* W2     = (const float*)d_in[5];
    float* ws  = (float*)d_ws;
    float* out = (float*)d_out;

    setup_kernel<<<1, 256, 0, stream>>>(t_span, ws);
    mega_kernel<<<dim3(NBLOCKS), dim3(256), 0, stream>>>(
        W1, W2, B_init, b1, y_init, ws, out);
}

// Round 6
// 611.686 us; speedup vs baseline: 6.1979x; 6.1979x over previous
//
#include <hip/hip_runtime.h>
#include <hip/hip_bf16.h>
#include <math.h>

// Problem constants (fixed by setup_inputs)
#define BB 128
#define DD 512
#define HH 1024
#define NB 32     // num_coeff_per_dim
#define MM 63     // 2N-1 simpson points
#define TT 16
#define ITERS 10

// ws layout (float units)
#define OFF_U       0        // 32 fp32
#define OFF_TTRUE   64       // 64 fp32 (tt[63]=0)
#define OFF_PHIOUT  128      // 512 fp32
#define OFF_PHIF_BF 1024     // bf16 [64 m][32 n]  (row 63 = 0)   = 1024 floats
#define OFF_QT_BF   2048     // bf16 [32 j][64 m]  (col 63 = 0)   = 1024 floats
#define HDRF        4096
#define OFF_BN      HDRF                     // fp32 [B][512][32]  = 2097152
#define OFF_BCT     (OFF_BN + 2097152)       // bf16 [B][32][512]  = 1048576 f
#define OFF_PT      (OFF_BCT + 1048576)      // bf16 [B][32][1024] = 2097152 f
#define OFF_W1T     (OFF_PT + 2097152)       // bf16 [1024][512]   = 262144 f
#define OFF_W2T     (OFF_W1T + 262144)       // bf16 [512][1024]   = 262144 f
// end = 5771264 floats = 23.1 MB

typedef __attribute__((ext_vector_type(8))) short bf16x8;
typedef __attribute__((ext_vector_type(4))) float f32x4;

static __device__ __forceinline__ unsigned short f2bf(float f) {
    unsigned int x = __builtin_bit_cast(unsigned int, f);
    unsigned int r = x + 0x7FFFu + ((x >> 16) & 1u);   // RNE
    return (unsigned short)(r >> 16);
}

static __device__ __forceinline__ void store4bf(unsigned short* p,
                                                float v0, float v1, float v2, float v3) {
    unsigned int lo = (unsigned int)f2bf(v0) | ((unsigned int)f2bf(v1) << 16);
    unsigned int hi = (unsigned int)f2bf(v2) | ((unsigned int)f2bf(v3) << 16);
    uint2 u; u.x = lo; u.y = hi;
    *(uint2*)p = u;   // 8B-aligned by construction
}

static __device__ __forceinline__ float tanh_fast(float x) {
    float e = exp2f(x * 2.88539008177793f);   // 2*log2(e)
    return 1.0f - 2.0f / (e + 1.0f);
}

// XOR-swizzled LDS A-tile addressing: tile [32 r][512 c] bf16, linear 32KB,
// byte = (r*1024 + c*2) ^ ((r&7)<<4). Bijective per row (XOR bits 4..6),
// keeps 16B alignment for b128 ops; spreads the 16-rows x 4-colgroups wave
// access pattern evenly over all 32 banks.
static __device__ __forceinline__ unsigned short* aS(unsigned short* smA, int r, int c16) {
    return (unsigned short*)((char*)smA + (((r << 10) + (c16 << 4)) ^ ((r & 7) << 4)));
}

// ---------------------------------------------------------------------------
// Setup: t grids, Phi_f, Phi_inv (double GJ, wave-parallel), Q = R@Phi_inv,
// u, Phi_out, bf16 tables.
// ---------------------------------------------------------------------------
__global__ __launch_bounds__(256) void setup_kernel(const float* __restrict__ t_span,
                                                    float* __restrict__ ws) {
    __shared__ double tsim[MM];
    __shared__ double ttrue_d[MM];
    __shared__ double wid[31];
    __shared__ double phid[NB * MM];   // [n][m]
    __shared__ double aug[NB * 64];    // [Phi | I]
    __shared__ double mlt[NB];
    __shared__ double Rl[MM * NB];
    __shared__ double Qd[MM * NB];     // [m][j]
    __shared__ int    piv_s;

    const int t    = threadIdx.x;  // 256 threads
    const int lane = t & 63;
    const int rgrp = t >> 6;
    const double PI = 3.14159265358979323846;
    const double t0 = (double)t_span[0];
    const double t1 = (double)t_span[TT - 1];

    if (t < MM) {
        double v;
        if ((t & 1) == 0) {
            int j = t >> 1;
            v = -cos(PI * (double)j / (double)(NB - 1));
        } else {
            int i = t >> 1;
            double a = -cos(PI * (double)i / (double)(NB - 1));
            double b = -cos(PI * (double)(i + 1) / (double)(NB - 1));
            v = 0.5 * (a + b);
        }
        tsim[t] = v;
        ttrue_d[t] = t0 + 0.5 * (t1 - t0) * (v + 1.0);
    }
    __syncthreads();
    if (t < 31) wid[t] = (ttrue_d[2 * t + 2] - ttrue_d[2 * t]) / 6.0;
    if (t < MM) ws[OFF_TTRUE + t] = (float)ttrue_d[t];
    if (t == 63) ws[OFF_TTRUE + 63] = 0.0f;

    if (t < MM) {
        double x = tsim[t];
        double r0 = 1.0, r1 = x;
        phid[0 * MM + t] = r0;
        phid[1 * MM + t] = r1;
        for (int n = 2; n < NB; n++) {
            double r2 = 2.0 * x * r1 - r0;
            phid[n * MM + t] = r2;
            r0 = r1; r1 = r2;
        }
    }
    __syncthreads();

    {   // phif_bf [m 64][n 32], row 63 = 0
        unsigned short* pf = (unsigned short*)(ws + OFF_PHIF_BF);
        for (int f = t; f < 64 * 32; f += 256) {
            int m = f >> 5, n = f & 31;
            pf[f] = f2bf(m < MM ? (float)phid[n * MM + m] : 0.0f);
        }
    }

    for (int f = t; f < NB * 64; f += 256) {
        int r = f >> 6, c = f & 63;
        double v;
        if (c < NB) v = phid[r * MM + 2 * c];
        else        v = ((c - NB) == r) ? 1.0 : 0.0;
        aug[f] = v;
    }
    __syncthreads();

    for (int k = 0; k < NB; k++) {
        if (t < 32) {
            double v = (t >= k) ? fabs(aug[t * 64 + k]) : -1.0;
            int idx = t;
            #pragma unroll
            for (int off = 16; off >= 1; off >>= 1) {
                double ov = __shfl_xor(v, off);
                int    oi = __shfl_xor(idx, off);
                if (ov > v) { v = ov; idx = oi; }
            }
            if (t == 0) piv_s = idx;
        }
        __syncthreads();
        const int p = piv_s;
        if (t < 64) {
            double pv   = aug[p * 64 + k];
            double rowp = aug[p * 64 + t];
            double rowk = aug[k * 64 + t];
            aug[k * 64 + t] = rowp / pv;
            if (p != k) aug[p * 64 + t] = rowk;
        }
        __syncthreads();
        if (t < 32) mlt[t] = (t == k) ? 0.0 : aug[t * 64 + k];
        __syncthreads();
        {
            double pk = aug[k * 64 + lane];
            #pragma unroll
            for (int i = 0; i < 8; i++) {
                int r = rgrp * 8 + i;
                aug[r * 64 + lane] -= mlt[r] * pk;
            }
        }
        __syncthreads();
    }

    if (t < MM) {
        double acc = 0.0;
        Rl[t * NB + 0] = 0.0;
        for (int i = 1; i < NB; i++) {
            int ip = i - 1;
            double w = 0.0;
            if (t == 2 * ip)     w += wid[ip];
            if (t == 2 * ip + 1) w += 4.0 * wid[ip];
            if (t == 2 * ip + 2) w += wid[ip];
            acc += w;
            Rl[t * NB + i] = acc;
        }
    }
    __syncthreads();

    for (int f = t; f < MM * NB; f += 256) {
        int m = f >> 5, j = f & 31;
        double s = 0.0;
        for (int i = 0; i < NB; i++) s += Rl[m * NB + i] * aug[i * 64 + 32 + j];
        Qd[f] = s;
    }
    __syncthreads();

    {   // qt_bf [j 32][m 64], col 63 = 0
        unsigned short* qt = (unsigned short*)(ws + OFF_QT_BF);
        for (int f = t; f < 32 * 64; f += 256) {
            int j = f >> 6, m = f & 63;
            qt[f] = f2bf(m < MM ? (float)Qd[m * NB + j] : 0.0f);
        }
    }
    if (t < NB) {
        double s = 0.0;
        for (int i = 0; i < NB; i++) s += aug[i * 64 + 32 + t];
        ws[OFF_U + t] = (float)s;
    }
    if (t < TT) {
        double x = -1.0 + 2.0 * ((double)t_span[t] - t0) / (t1 - t0);
        double r0 = 1.0, r1 = x;
        ws[OFF_PHIOUT + 0 * TT + t] = 1.0f;
        ws[OFF_PHIOUT + 1 * TT + t] = (float)x;
        for (int n = 2; n < NB; n++) {
            double r2 = 2.0 * x * r1 - r0;
            ws[OFF_PHIOUT + n * TT + t] = (float)r2;
            r0 = r1; r1 = r2;
        }
    }
}

// ---------------------------------------------------------------------------
// Transpose fp32 (R x C) -> bf16 (C x R)
// ---------------------------------------------------------------------------
__global__ __launch_bounds__(256) void transpose_f32_bf16(
        const float* __restrict__ in, unsigned short* __restrict__ out,
        int R, int C) {
    __shared__ float tile[32][33];
    const int t = threadIdx.x;
    const int tc = blockIdx.x, tr = blockIdx.y;
    const int c = tc * 32 + (t & 31);
    #pragma unroll
    for (int i = 0; i < 4; i++) {
        int rl = (t >> 5) + i * 8;
        tile[rl][t & 31] = in[(size_t)(tr * 32 + rl) * C + c];
    }
    __syncthreads();
    #pragma unroll
    for (int i = 0; i < 4; i++) {
        int orl = (t >> 5) + i * 8;            // local col of input
        int orow = tc * 32 + orl;
        int ocol = tr * 32 + (t & 31);
        out[(size_t)orow * R + ocol] = f2bf(tile[t & 31][orl]);
    }
}

// B_init [b][d][n] fp32 -> Bct [b][n][d] bf16
__global__ __launch_bounds__(256) void binit_kernel(
        const float* __restrict__ Bi, unsigned short* __restrict__ Bct) {
    __shared__ float tile[32][33];
    const int t = threadIdx.x;
    const int b = blockIdx.y, d0 = blockIdx.x * 32;
    #pragma unroll
    for (int i = 0; i < 4; i++) {
        int f = i * 256 + t;
        int dd = f >> 5, n = f & 31;
        tile[dd][n] = Bi[((size_t)b * DD + d0 + dd) * NB + n];
    }
    __syncthreads();
    #pragma unroll
    for (int i = 0; i < 4; i++) {
        int f = i * 256 + t;
        int n = f >> 5, dd = f & 31;
        Bct[((size_t)b * NB + n) * DD + d0 + dd] = f2bf(tile[dd][n]);
    }
}

// ---------------------------------------------------------------------------
// K1: per block (b, 128 h). A-tile (Bct b-slice 32x512) staged once in LDS
// (XOR-swizzled), shared by all 4 waves. Phase A: G = A W1^T (MFMA, B from
// global). Phase B: Z = Phi_f^T G, tanh, P = Q^T T. t_sb overlays A_s.
// LDS: 32768 (A_s | t_sb) + 8192 (g_sb) = 40960 B -> 4 blocks/CU.
// ---------------------------------------------------------------------------
__global__ __launch_bounds__(256) void k1_kernel(
        const unsigned short* __restrict__ Bct,  // [B][32 n][512 d] bf16
        const unsigned short* __restrict__ W1t,  // [1024 h][512 d] bf16
        const float* __restrict__ b1,            // [1024]
        const float* __restrict__ ws,
        unsigned short* __restrict__ Pt)         // [B][32 j][1024 h] bf16
{
    __shared__ __align__(16) char smem[40960];
    unsigned short* smA  = (unsigned short*)smem;           // A [32][512] swz (phase A)
    unsigned short* t_sb = (unsigned short*)smem;           // [128][72] (phase B, overlays A)
    unsigned short* g_sb = (unsigned short*)(smem + 32768); // [128][32]

    const int t    = threadIdx.x;
    const int lane = t & 63;
    const int w    = t >> 6;       // wave 0..3
    const int q    = lane >> 4;    // quad 0..3
    const int l15  = lane & 15;
    const int b    = blockIdx.y;
    const int h0   = blockIdx.x * 128;
    const int hw   = h0 + w * 32;  // wave's global h base

    // ---- stage A = Bct[b] (32x512 bf16 = 32KB; 8x 16B per thread) ----
    {
        const unsigned short* A0 = Bct + (size_t)b * NB * DD;
        #pragma unroll
        for (int i = 0; i < 8; i++) {
            int c = i * 256 + t;           // 0..2047 16B-chunks
            int r = c >> 6, c16 = c & 63;
            bf16x8 v = *(const bf16x8*)(A0 + (size_t)r * DD + c16 * 8);
            *(bf16x8*)aS(smA, r, c16) = v;
        }
    }
    __syncthreads();

    // ---- Phase A: G = A W1^T, M=32(n) x N=32(h/wave) x K=512 ----
    f32x4 acc[2][2] = {};
    #pragma unroll 4
    for (int d0 = 0; d0 < DD; d0 += 32) {
        int c16 = (d0 >> 3) + q;
        bf16x8 a0 = *(const bf16x8*)aS(smA, l15, c16);
        bf16x8 a1 = *(const bf16x8*)aS(smA, 16 + l15, c16);
        bf16x8 bb0 = *(const bf16x8*)(W1t + (size_t)(hw + l15) * DD + d0 + q * 8);
        bf16x8 bb1 = *(const bf16x8*)(W1t + (size_t)(hw + 16 + l15) * DD + d0 + q * 8);
        acc[0][0] = __builtin_amdgcn_mfma_f32_16x16x32_bf16(a0, bb0, acc[0][0], 0, 0, 0);
        acc[0][1] = __builtin_amdgcn_mfma_f32_16x16x32_bf16(a0, bb1, acc[0][1], 0, 0, 0);
        acc[1][0] = __builtin_amdgcn_mfma_f32_16x16x32_bf16(a1, bb0, acc[1][0], 0, 0, 0);
        acc[1][1] = __builtin_amdgcn_mfma_f32_16x16x32_bf16(a1, bb1, acc[1][1], 0, 0, 0);
    }
    // write G to g_sb[h_loc][n] bf16
    #pragma unroll
    for (int mt = 0; mt < 2; mt++)
        #pragma unroll
        for (int nt = 0; nt < 2; nt++) {
            int hl = w * 32 + nt * 16 + l15;
            store4bf(&g_sb[hl * 32 + mt * 16 + q * 4],
                     acc[mt][nt][0], acc[mt][nt][1], acc[mt][nt][2], acc[mt][nt][3]);
        }
    __syncthreads();   // also: all A_s reads complete -> t_sb may overlay

    // ---- Z = Phi_f^T G : M=64(m) x N=32(h/wave) x K=32(n) ----
    f32x4 zacc[4][2] = {};
    const unsigned short* PF = (const unsigned short*)(ws + OFF_PHIF_BF);
    bf16x8 gb[2];
    #pragma unroll
    for (int nt = 0; nt < 2; nt++)
        gb[nt] = *(const bf16x8*)(&g_sb[(w * 32 + nt * 16 + l15) * 32 + q * 8]);
    #pragma unroll
    for (int mt = 0; mt < 4; mt++) {
        bf16x8 af = *(const bf16x8*)(PF + (mt * 16 + l15) * 32 + q * 8);
        zacc[mt][0] = __builtin_amdgcn_mfma_f32_16x16x32_bf16(af, gb[0], zacc[mt][0], 0, 0, 0);
        zacc[mt][1] = __builtin_amdgcn_mfma_f32_16x16x32_bf16(af, gb[1], zacc[mt][1], 0, 0, 0);
    }

    // bias + tanh + write t_sb[h_loc][m] bf16
    const float* TTp = ws + OFF_TTRUE;
    float b1v[2] = { b1[hw + l15], b1[hw + 16 + l15] };
    #pragma unroll
    for (int mt = 0; mt < 4; mt++) {
        float4 ttv = *(const float4*)(TTp + mt * 16 + q * 4);
        #pragma unroll
        for (int nt = 0; nt < 2; nt++) {
            int hl = w * 32 + nt * 16 + l15;
            float v0 = tanh_fast(zacc[mt][nt][0] + ttv.x * b1v[nt]);
            float v1 = tanh_fast(zacc[mt][nt][1] + ttv.y * b1v[nt]);
            float v2 = tanh_fast(zacc[mt][nt][2] + ttv.z * b1v[nt]);
            float v3 = tanh_fast(zacc[mt][nt][3] + ttv.w * b1v[nt]);
            store4bf(&t_sb[hl * 72 + mt * 16 + q * 4], v0, v1, v2, v3);
        }
    }
    __syncthreads();

    // ---- P = Q^T T : M=32(j) x N=32(h/wave) x K=64(m) ----
    f32x4 pacc[2][2] = {};
    const unsigned short* QT = (const unsigned short*)(ws + OFF_QT_BF);
    #pragma unroll
    for (int ks = 0; ks < 2; ks++) {
        bf16x8 bt[2];
        #pragma unroll
        for (int nt = 0; nt < 2; nt++)
            bt[nt] = *(const bf16x8*)(&t_sb[(w * 32 + nt * 16 + l15) * 72 + ks * 32 + q * 8]);
        #pragma unroll
        for (int jt = 0; jt < 2; jt++) {
            bf16x8 aq = *(const bf16x8*)(QT + (jt * 16 + l15) * 64 + ks * 32 + q * 8);
            pacc[jt][0] = __builtin_amdgcn_mfma_f32_16x16x32_bf16(aq, bt[0], pacc[jt][0], 0, 0, 0);
            pacc[jt][1] = __builtin_amdgcn_mfma_f32_16x16x32_bf16(aq, bt[1], pacc[jt][1], 0, 0, 0);
        }
    }

    // store P_t[b][j][h] bf16
    #pragma unroll
    for (int jt = 0; jt < 2; jt++)
        #pragma unroll
        for (int nt = 0; nt < 2; nt++) {
            int hg = hw + nt * 16 + l15;
            #pragma unroll
            for (int r = 0; r < 4; r++) {
                int j = jt * 16 + q * 4 + r;
                Pt[((size_t)b * NB + j) * HH + hg] = f2bf(pacc[jt][nt][r]);
            }
        }
}

// ---------------------------------------------------------------------------
// K2: Bn[b,d,j] = sum_h P[b,h,j] W2[h,d] + y u[j]  via MFMA.
// A = Pt[b] (32x1024) staged in LDS in two 32x512 chunks (XOR-swizzled),
// shared by all 4 waves. Bct written on non-last iters; Bn only on last
// (saves 9x8MB fp32 + 1MB bf16 of dead HBM writes).
// ---------------------------------------------------------------------------
__global__ __launch_bounds__(256) void k2_kernel(
        const unsigned short* __restrict__ Pt,   // [B][32 j][1024 h] bf16
        const unsigned short* __restrict__ W2t,  // [512 d][1024 h] bf16
        const float* __restrict__ y_init,        // [B][512]
        const float* __restrict__ ws,
        float* __restrict__ Bn,                  // [B][512][32] fp32 (last iter)
        unsigned short* __restrict__ Bct,        // [B][32][512] bf16 (next iter)
        int last)
{
    __shared__ __align__(16) char smem[32768];
    unsigned short* smA = (unsigned short*)smem;   // A chunk [32][512] swz
    float*          ls  = (float*)smem;            // 4x[32*33] f32 (epilogue overlay)

    const int t    = threadIdx.x;
    const int lane = t & 63;
    const int w    = t >> 6;
    const int q    = lane >> 4;
    const int l15  = lane & 15;
    const int b    = blockIdx.y;
    const int d0   = blockIdx.x * 128;
    const int dw   = d0 + w * 32;

    f32x4 acc[2][2] = {};
    #pragma unroll 1
    for (int chunk = 0; chunk < 2; chunk++) {
        // stage A chunk: Pt[b][j][chunk*512 .. +512)
        {
            const unsigned short* A0 = Pt + (size_t)b * NB * HH + chunk * 512;
            #pragma unroll
            for (int i = 0; i < 8; i++) {
                int c = i * 256 + t;
                int r = c >> 6, c16 = c & 63;
                bf16x8 v = *(const bf16x8*)(A0 + (size_t)r * HH + c16 * 8);
                *(bf16x8*)aS(smA, r, c16) = v;
            }
        }
        __syncthreads();
        #pragma unroll 4
        for (int hc = 0; hc < 512; hc += 32) {
            int c16 = (hc >> 3) + q;
            bf16x8 a0 = *(const bf16x8*)aS(smA, l15, c16);
            bf16x8 a1 = *(const bf16x8*)aS(smA, 16 + l15, c16);
            bf16x8 bb0 = *(const bf16x8*)(W2t + (size_t)(dw + l15) * HH + chunk * 512 + hc + q * 8);
            bf16x8 bb1 = *(const bf16x8*)(W2t + (size_t)(dw + 16 + l15) * HH + chunk * 512 + hc + q * 8);
            acc[0][0] = __builtin_amdgcn_mfma_f32_16x16x32_bf16(a0, bb0, acc[0][0], 0, 0, 0);
            acc[0][1] = __builtin_amdgcn_mfma_f32_16x16x32_bf16(a0, bb1, acc[0][1], 0, 0, 0);
            acc[1][0] = __builtin_amdgcn_mfma_f32_16x16x32_bf16(a1, bb0, acc[1][0], 0, 0, 0);
            acc[1][1] = __builtin_amdgcn_mfma_f32_16x16x32_bf16(a1, bb1, acc[1][1], 0, 0, 0);
        }
        __syncthreads();   // A_s safe to restage / overlay
    }

    // epilogue: add y*u; non-last -> Bct bf16; last -> stage + fp32 Bn
    const float* U = ws + OFF_U;
    float yv[2] = { y_init[(size_t)b * DD + dw + l15],
                    y_init[(size_t)b * DD + dw + 16 + l15] };
    #pragma unroll
    for (int mt = 0; mt < 2; mt++) {
        float4 uv = *(const float4*)(U + mt * 16 + q * 4);
        #pragma unroll
        for (int nt = 0; nt < 2; nt++) {
            int dl = nt * 16 + l15;         // 0..31 within wave
            #pragma unroll
            for (int r = 0; r < 4; r++) {
                int j = mt * 16 + q * 4 + r;
                float uvr = (r == 0) ? uv.x : (r == 1) ? uv.y : (r == 2) ? uv.z : uv.w;
                float val = acc[mt][nt][r] + yv[nt] * uvr;
                if (!last) Bct[((size_t)b * NB + j) * DD + dw + dl] = f2bf(val);
                else       ls[w * 1056 + j * 33 + dl] = val;
            }
        }
    }
    if (last) {
        __syncthreads();
        // coalesced fp32 Bn write: [b][d][j]
        #pragma unroll
        for (int it = 0; it < 16; it++) {
            int f = it * 64 + lane;
            int d_l = f >> 5, j2 = f & 31;
            Bn[((size_t)b * DD + dw + d_l) * NB + j2] = ls[w * 1056 + j2 * 33 + d_l];
        }
    }
}

// ---------------------------------------------------------------------------
// K3: out0[t,b,d] = sum_n Bn[b,d,n]*Phi_out[n,t] ; out1 = Bn
// ---------------------------------------------------------------------------
__global__ __launch_bounds__(256) void k3_kernel(
        const float* __restrict__ ws_c, float* __restrict__ out) {
    __shared__ float rows_s[64 * 33];
    __shared__ float phiout_s[NB * TT];

    const int t = threadIdx.x;
    const int r0 = blockIdx.x * 64;
    const float* Bf = ws_c + OFF_BN;

    for (int f = t; f < NB * TT; f += 256) phiout_s[f] = ws_c[OFF_PHIOUT + f];

    float vals[8];
    {
        int f = t;
        #pragma unroll
        for (int i = 0; i < 8; i++, f += 256) {
            float v = Bf[(size_t)r0 * NB + f];
            rows_s[(f >> 5) * 33 + (f & 31)] = v;
            vals[i] = v;
        }
    }
    float* out1 = out + (size_t)TT * BB * DD;
    {
        int f = t;
        #pragma unroll
        for (int i = 0; i < 8; i++, f += 256) out1[(size_t)r0 * NB + f] = vals[i];
    }
    __syncthreads();

    #pragma unroll
    for (int i = 0; i < 4; i++) {
        int idx = i * 256 + t;
        int tt = idx >> 6, rl = idx & 63;
        float s = 0.f;
        #pragma unroll
        for (int n = 0; n < NB; n++)
            s += rows_s[rl * 33 + n] * phiout_s[n * TT + tt];
        out[(size_t)tt * (BB * DD) + r0 + rl] = s;
    }
}

// ---------------------------------------------------------------------------
extern "C" void kernel_launch(void* const* d_in, const int* in_sizes, int n_in,
                              void* d_out, int out_size, void* d_ws, size_t ws_size,
                              hipStream_t stream) {
    const float* t_span = (const float*)d_in[0];
    const float* y_init = (const float*)d_in[1];
    const float* B_init = (const float*)d_in[2];
    const float* W1     = (const float*)d_in[3];
    const float* b1     = (const float*)d_in[4];
    const float* W2     = (const float*)d_in[5];
    float* ws  = (float*)d_ws;
    float* out = (float*)d_out;

    unsigned short* W1t = (unsigned short*)(ws + OFF_W1T);
    unsigned short* W2t = (unsigned short*)(ws + OFF_W2T);
    unsigned short* Bct = (unsigned short*)(ws + OFF_BCT);
    unsigned short* Pt  = (unsigned short*)(ws + OFF_PT);
    float*          Bn  = ws + OFF_BN;

    setup_kernel<<<1, 256, 0, stream>>>(t_span, ws);
    transpose_f32_bf16<<<dim3(HH / 32, DD / 32), 256, 0, stream>>>(W1, W1t, DD, HH);
    transpose_f32_bf16<<<dim3(DD / 32, HH / 32), 256, 0, stream>>>(W2, W2t, HH, DD);
    binit_kernel<<<dim3(DD / 32, BB), 256, 0, stream>>>(B_init, Bct);

    for (int it = 0; it < ITERS; it++) {
        k1_kernel<<<dim3(HH / 128, BB), 256, 0, stream>>>(Bct, W1t, b1, ws, Pt);
        k2_kernel<<<dim3(DD / 128, BB), 256, 0, stream>>>(Pt, W2t, y_init, ws, Bn, Bct,
                                                          it == ITERS - 1 ? 1 : 0);
    }
    k3_kernel<<<dim3((BB * DD) / 64), 256, 0, stream>>>(ws, out);
}